// Round 11
// baseline (115.059 us; speedup 1.0000x reference)
//
#include <hip/hip_runtime.h>
#include <hip/hip_bf16.h>
#include <stdint.h>

// C[4096,10532] = inputs[4096,256] @ concat(lut,queue)[10532,256]^T  (fp32 out)
// R11: INSTRUMENTATION ROUND. Body = R6-exact (best known, 65.5us total).
// The gemm runs its entire work TWICE inside one dispatch (deterministic:
// identical passes, identical final output) so the dispatch (~113us) rises
// above the harness's ~100us fill kernels into rocprof's top-5 and we finally
// see WRITE_SIZE / FETCH_SIZE / MfmaUtil / Occupancy for the fast structure.
// Seven structural variants are pinned at gemm ~57-60us; these counters
// discriminate write-amplification vs scheduling-serialization vs stall.

#define M_DIM 4096
#define K_DIM 256
#define N_LUT 5532
#define N_Q   5000
#define N_DIM (N_LUT + N_Q)   // 10532
#define NT_M  32              // 4096/128
#define NT_N  83              // ceil(10532/128)
#define N_PAD (NT_N * 128)    // 10624

typedef _Float16 f16x8 __attribute__((ext_vector_type(8)));
typedef float f32x4 __attribute__((ext_vector_type(4)));

__device__ __forceinline__ unsigned short f2h(float f) {
  union { _Float16 h; unsigned short u; } v;
  v.h = (_Float16)f;   // v_cvt_f16_f32, RNE
  return v.u;
}

// ---------------- convert fp32 -> f16 into workspace ----------------
__global__ __launch_bounds__(256) void convert_kernel(
    const float* __restrict__ inp, const float* __restrict__ lut,
    const float* __restrict__ que, unsigned short* __restrict__ Abf,
    unsigned short* __restrict__ Bbf) {
  const int AV = M_DIM * K_DIM / 4;  // 262144 float4s for A
  int i = blockIdx.x * 256 + threadIdx.x;  // grid sized exactly
  float4 x;
  unsigned short* dst;
  if (i < AV) {
    x = ((const float4*)inp)[i];
    dst = Abf + i * 4;
  } else {
    int e = (i - AV) * 4;          // element index in padded B
    int row = e >> 8;              // /256
    int col = e & 255;
    if (row < N_LUT)
      x = *(const float4*)(lut + (size_t)row * K_DIM + col);
    else if (row < N_DIM)
      x = *(const float4*)(que + (size_t)(row - N_LUT) * K_DIM + col);
    else
      x = make_float4(0.f, 0.f, 0.f, 0.f);
    dst = Bbf + e;
  }
  ushort4 o;
  o.x = f2h(x.x); o.y = f2h(x.y); o.z = f2h(x.z); o.w = f2h(x.w);
  *(ushort4*)dst = o;
}

// ---------------- GEMM: C = A * B^T, both [rows][K] f16 ----------------
#define GLDS16(gsrc, ldst)                                                  \
  __builtin_amdgcn_global_load_lds(                                         \
      (__attribute__((address_space(1))) void*)(gsrc),                      \
      (__attribute__((address_space(3))) void*)(ldst), 16, 0, 0)

__global__ __launch_bounds__(256, 2) void gemm_kernel(
    const unsigned short* __restrict__ A, const unsigned short* __restrict__ B,
    float* __restrict__ C) {
  // single-buffered 128x64 f16 tiles: 32 KB total
  __shared__ __align__(16) unsigned short As[128 * 64];
  __shared__ __align__(16) unsigned short Bs[128 * 64];

  const int t = threadIdx.x;
  const int lane = t & 63;
  const int wave = t >> 6;         // 4 waves
  const int wm = wave >> 1;        // 2x2 wave grid, each 64x64 output
  const int wn = wave & 1;

  // XCD chunking (nwg = 2656 = 8 * 332), bn-fast within each chunk
  const int nwg = NT_M * NT_N;
  const int cpx = nwg >> 3;        // 332
  int bid = blockIdx.x;
  int wg = (bid & 7) * cpx + (bid >> 3);
  const int bn = wg % NT_N;        // col-fast: col-neighbors concurrent
  const int bm = wg / NT_N;
  const int brow = bm * 128;
  const int bcol = bn * 128;

  // staging with PRE-SWIZZLED global source (LDS dest linear):
  // lds[row][ch] = global[row][ch ^ (row&7)]  (16B chunks)
  const int trow = t >> 3;                       // 0..31
  const int tcs = (((t & 7) ^ (trow & 7)) * 8);  // swizzled col, elements
  const unsigned short* gaBase = A + (size_t)(brow + trow) * K_DIM + tcs;
  const unsigned short* gbBase = B + (size_t)(bcol + trow) * K_DIM + tcs;
  const int ldsOff = wave * 512;   // elements; HW adds lane*16 bytes

#define STAGE(kt)                                                            \
  do {                                                                       \
    _Pragma("unroll") for (int is = 0; is < 4; ++is) {                       \
      GLDS16(gaBase + (size_t)is * 32 * K_DIM + (kt) * 64,                   \
             As + is * 2048 + ldsOff);                                       \
      GLDS16(gbBase + (size_t)is * 32 * K_DIM + (kt) * 64,                   \
             Bs + is * 2048 + ldsOff);                                       \
    }                                                                        \
  } while (0)

  const int lr = lane & 15;
  const int rsw = lane & 7;        // = row&7 for all fragment rows
  const int cq = lane >> 4;        // quarter-wave id = base col chunk
  const int cc4 = cq * 4;

#pragma unroll 1
  for (int rep = 0; rep < 2; ++rep) {   // instrumentation: 2 identical passes
    f32x4 acc[4][4];
#pragma unroll
    for (int i = 0; i < 4; ++i)
#pragma unroll
      for (int j = 0; j < 4; ++j) acc[i][j] = (f32x4){0.f, 0.f, 0.f, 0.f};

#pragma unroll
    for (int kt = 0; kt < 4; ++kt) { // K = 256 = 4 * 64
      STAGE(kt);
      __syncthreads();               // vmcnt(0)+lgkmcnt(0) drain + barrier

#pragma unroll
      for (int kk = 0; kk < 64; kk += 32) {
        const int ch = ((kk >> 3) + cq) ^ rsw;   // swizzled 16B chunk
        f16x8 a[4], b[4];
#pragma unroll
        for (int i = 0; i < 4; ++i)
          a[i] = *(const f16x8*)&As[(wm * 64 + i * 16 + lr) * 64 + ch * 8];
#pragma unroll
        for (int j = 0; j < 4; ++j)
          b[j] = *(const f16x8*)&Bs[(wn * 64 + j * 16 + lr) * 64 + ch * 8];
        // swapped operands: C-row = i*16+lr, C-cols = j*16 + cc4 + reg
#pragma unroll
        for (int i = 0; i < 4; ++i)
#pragma unroll
          for (int j = 0; j < 4; ++j)
            acc[i][j] = __builtin_amdgcn_mfma_f32_16x16x32_f16(b[j], a[i],
                                                               acc[i][j], 0, 0, 0);
      }
      __syncthreads();               // all waves done reading before next STAGE
    }

    // store (reads only regs; rep2's STAGE may overwrite LDS safely after
    // the kt=3 __syncthreads above)
#pragma unroll
    for (int i = 0; i < 4; ++i) {
      size_t rowBase = (size_t)(brow + wm * 64 + i * 16 + lr) * N_DIM;
#pragma unroll
      for (int j = 0; j < 4; ++j) {
        int col = bcol + wn * 64 + j * 16 + cc4;
        if (col < N_DIM)
          *(f32x4*)&C[rowBase + col] = acc[i][j];
      }
    }
  }
#undef STAGE
}

extern "C" void kernel_launch(void* const* d_in, const int* in_sizes, int n_in,
                              void* d_out, int out_size, void* d_ws, size_t ws_size,
                              hipStream_t stream) {
  const float* inp = (const float*)d_in[0];   // inputs [4096,256]
  // d_in[1] targets, d_in[2] gt_flag: unused by the forward similarity
  const float* lut = (const float*)d_in[3];   // [5532,256]
  const float* que = (const float*)d_in[4];   // [5000,256]
  float* C = (float*)d_out;                   // [4096,10532]

  unsigned short* Abf = (unsigned short*)d_ws;
  unsigned short* Bbf = Abf + (size_t)M_DIM * K_DIM;  // ~7.6 MB of ws

  const int conv_blocks = (M_DIM * K_DIM / 4 + N_PAD * K_DIM / 4) / 256;
  convert_kernel<<<conv_blocks, 256, 0, stream>>>(inp, lut, que, Abf, Bbf);

  gemm_kernel<<<NT_M * NT_N, 256, 0, stream>>>(Abf, Bbf, C);
}

// Round 12
// 65.320 us; speedup vs baseline: 1.7615x; 1.7615x over previous
//
#include <hip/hip_runtime.h>
#include <hip/hip_bf16.h>
#include <stdint.h>

// C[4096,10532] = inputs[4096,256] @ concat(lut,queue)[10532,256]^T  (fp32 out)
// R12: BM=128 x BN=256 tile (BK=64, 48 KB LDS, 512 thr = 8 waves as 2x4),
// bm-FAST XCD chunk order. Rationale from R11's clean counters: WRITE=ideal
// 171 MB, FETCH=85 MB/pass (10x compulsory) is the only excess. bm-fast makes
// the 128-KB B tile reused by 32 consecutive blocks and leaves the full 2-MB
// A panel L2-resident per XCD -> staging becomes L2-hits. Bigger tile also
// halves barrier drains per output byte. Verified pieces (swizzle, swapped
// MFMA, dwordx4 stores, 2-phase syncthreads) unchanged.

#define M_DIM 4096
#define K_DIM 256
#define N_LUT 5532
#define N_Q   5000
#define N_DIM (N_LUT + N_Q)   // 10532
#define NT_M  32              // 4096/128
#define NT_N  42              // ceil(10532/256)
#define N_PAD (NT_N * 256)    // 10752

typedef _Float16 f16x8 __attribute__((ext_vector_type(8)));
typedef float f32x4 __attribute__((ext_vector_type(4)));

__device__ __forceinline__ unsigned short f2h(float f) {
  union { _Float16 h; unsigned short u; } v;
  v.h = (_Float16)f;   // v_cvt_f16_f32, RNE
  return v.u;
}

// ---------------- convert fp32 -> f16 into workspace ----------------
__global__ __launch_bounds__(256) void convert_kernel(
    const float* __restrict__ inp, const float* __restrict__ lut,
    const float* __restrict__ que, unsigned short* __restrict__ Abf,
    unsigned short* __restrict__ Bbf) {
  const int AV = M_DIM * K_DIM / 4;  // 262144 float4s for A
  int i = blockIdx.x * 256 + threadIdx.x;  // grid sized exactly
  float4 x;
  unsigned short* dst;
  if (i < AV) {
    x = ((const float4*)inp)[i];
    dst = Abf + i * 4;
  } else {
    int e = (i - AV) * 4;          // element index in padded B
    int row = e >> 8;              // /256
    int col = e & 255;
    if (row < N_LUT)
      x = *(const float4*)(lut + (size_t)row * K_DIM + col);
    else if (row < N_DIM)
      x = *(const float4*)(que + (size_t)(row - N_LUT) * K_DIM + col);
    else
      x = make_float4(0.f, 0.f, 0.f, 0.f);
    dst = Bbf + e;
  }
  ushort4 o;
  o.x = f2h(x.x); o.y = f2h(x.y); o.z = f2h(x.z); o.w = f2h(x.w);
  *(ushort4*)dst = o;
}

// ---------------- GEMM: C = A * B^T, both [rows][K] f16 ----------------
#define GLDS16(gsrc, ldst)                                                  \
  __builtin_amdgcn_global_load_lds(                                         \
      (__attribute__((address_space(1))) void*)(gsrc),                      \
      (__attribute__((address_space(3))) void*)(ldst), 16, 0, 0)

__global__ __launch_bounds__(512, 4) void gemm_kernel(
    const unsigned short* __restrict__ A, const unsigned short* __restrict__ B,
    float* __restrict__ C) {
  // single-buffered tiles: A 128x64 f16 = 16 KB, B 256x64 f16 = 32 KB
  __shared__ __align__(16) unsigned short As[128 * 64];
  __shared__ __align__(16) unsigned short Bs[256 * 64];

  const int t = threadIdx.x;
  const int lane = t & 63;
  const int wave = t >> 6;         // 8 waves: 2 (m) x 4 (n), each 64x64 out
  const int wm = wave >> 2;        // 0..1
  const int wn = wave & 3;         // 0..3

  // XCD chunking: nwg = 32*42 = 1344 = 8 * 168. bm-FAST within chunk:
  // 32 consecutive wg share one 128-KB B tile; full A panel (2 MB) stays
  // L2-resident across the chunk's 5.25 bn sweeps.
  const int nwg = NT_M * NT_N;
  const int cpx = nwg >> 3;        // 168
  int bid = blockIdx.x;
  int wg = (bid & 7) * cpx + (bid >> 3);
  const int bm = wg & 31;          // bm-fast
  const int bn = wg >> 5;          // 0..41
  const int brow = bm * 128;
  const int bcol = bn * 256;

  // staging with PRE-SWIZZLED global source (LDS dest linear):
  // lds[row][ch] = global[row][ch ^ (row&7)]  (16B chunks, 8 per 128-B row)
  const int trow = t >> 3;                       // 0..63
  const int tcs = (((t & 7) ^ (trow & 7)) * 8);  // swizzled col, elements
  const unsigned short* gaBase = A + (size_t)(brow + trow) * K_DIM + tcs;
  const unsigned short* gbBase = B + (size_t)(bcol + trow) * K_DIM + tcs;
  const int ldsOff = wave * 512;   // elements; HW adds lane*16 bytes
  // per round: 512 thr x 16 B = 8 KB = 64 rows. A: 2 rounds, B: 4 rounds.

#define STAGE(kt)                                                            \
  do {                                                                       \
    _Pragma("unroll") for (int r = 0; r < 2; ++r)                            \
      GLDS16(gaBase + (size_t)r * 64 * K_DIM + (kt) * 64,                    \
             As + r * 4096 + ldsOff);                                        \
    _Pragma("unroll") for (int r = 0; r < 4; ++r)                            \
      GLDS16(gbBase + (size_t)r * 64 * K_DIM + (kt) * 64,                    \
             Bs + r * 4096 + ldsOff);                                        \
  } while (0)

  f32x4 acc[4][4] = {};
  const int lr = lane & 15;
  const int rsw = lane & 7;        // = row&7 for all fragment rows
  const int cq = lane >> 4;        // quarter-wave id = base col chunk
  const int cc4 = cq * 4;

#pragma unroll
  for (int kt = 0; kt < 4; ++kt) { // K = 256 = 4 * 64
    STAGE(kt);
    __syncthreads();               // vmcnt(0)+lgkmcnt(0) drain + barrier

#pragma unroll
    for (int kk = 0; kk < 64; kk += 32) {
      const int ch = ((kk >> 3) + cq) ^ rsw;   // swizzled 16B chunk, 0..7
      f16x8 b[4];
#pragma unroll
      for (int j = 0; j < 4; ++j)
        b[j] = *(const f16x8*)&Bs[(wn * 64 + j * 16 + lr) * 64 + ch * 8];
#pragma unroll
      for (int i = 0; i < 4; ++i) {
        f16x8 a = *(const f16x8*)&As[(wm * 64 + i * 16 + lr) * 64 + ch * 8];
        // swapped operands: C-row = i*16+lr, C-cols = j*16 + cc4 + reg
#pragma unroll
        for (int j = 0; j < 4; ++j)
          acc[i][j] = __builtin_amdgcn_mfma_f32_16x16x32_f16(b[j], a,
                                                             acc[i][j], 0, 0, 0);
      }
    }
    __syncthreads();               // all waves done reading before next STAGE
  }

  // epilogue: lane holds 4 consecutive C-cols -> dwordx4 stores
#pragma unroll
  for (int i = 0; i < 4; ++i) {
    size_t rowBase = (size_t)(brow + wm * 64 + i * 16 + lr) * N_DIM;
#pragma unroll
    for (int j = 0; j < 4; ++j) {
      int col = bcol + wn * 64 + j * 16 + cc4;
      if (col < N_DIM)             // N_DIM%4==0: f32x4 granule fully valid
        *(f32x4*)&C[rowBase + col] = acc[i][j];
    }
  }
#undef STAGE
}

extern "C" void kernel_launch(void* const* d_in, const int* in_sizes, int n_in,
                              void* d_out, int out_size, void* d_ws, size_t ws_size,
                              hipStream_t stream) {
  const float* inp = (const float*)d_in[0];   // inputs [4096,256]
  // d_in[1] targets, d_in[2] gt_flag: unused by the forward similarity
  const float* lut = (const float*)d_in[3];   // [5532,256]
  const float* que = (const float*)d_in[4];   // [5000,256]
  float* C = (float*)d_out;                   // [4096,10532]

  unsigned short* Abf = (unsigned short*)d_ws;
  unsigned short* Bbf = Abf + (size_t)M_DIM * K_DIM;  // ~7.7 MB of ws

  // (4096*256 + 10752*256)/4 float4s / 256 threads = 3712 blocks exact
  const int conv_blocks = (M_DIM * K_DIM / 4 + N_PAD * K_DIM / 4) / 256;
  convert_kernel<<<conv_blocks, 256, 0, stream>>>(inp, lut, que, Abf, Bbf);

  gemm_kernel<<<NT_M * NT_N, 512, 0, stream>>>(Abf, Bbf, C);
}

// Round 13
// 61.463 us; speedup vs baseline: 1.8720x; 1.0627x over previous
//
#include <hip/hip_runtime.h>
#include <hip/hip_bf16.h>
#include <stdint.h>

// C[4096,10532] = inputs[4096,256] @ concat(lut,queue)[10532,256]^T  (fp32 out)
// R13: PERSISTENT-B kernel. 252 blocks (42 bn x 6 m-strips), 512 threads.
// Each block loads its B tile (256 cols x K=256 f16 = 128 KB) into LDS ONCE,
// then walks 21-22 m-subtiles (32 rows), double-buffering a 16-KB A subtile.
// Eliminates the 339-MB logical B re-staging that fought the 172-MB C-store
// stream for L2/fabric (R11: 257 MB fabric @ 4.7 TB/s mixed = the wall).
// LDS = 128 + 2x16 = 160 KiB (full CU, 1 block/CU; HK 160-KB precedent).

#define M_DIM 4096
#define K_DIM 256
#define N_LUT 5532
#define N_Q   5000
#define N_DIM (N_LUT + N_Q)   // 10532
#define BN    256
#define NT_N  42              // ceil(10532/256)
#define N_PAD (NT_N * 256)    // 10752
#define NSTRIP 6              // m-strips; 128 subtiles of 32 rows split 21/22

typedef _Float16 f16x8 __attribute__((ext_vector_type(8)));
typedef float f32x4 __attribute__((ext_vector_type(4)));

__device__ __forceinline__ unsigned short f2h(float f) {
  union { _Float16 h; unsigned short u; } v;
  v.h = (_Float16)f;   // v_cvt_f16_f32, RNE
  return v.u;
}

// ---------------- convert fp32 -> f16 into workspace ----------------
__global__ __launch_bounds__(256) void convert_kernel(
    const float* __restrict__ inp, const float* __restrict__ lut,
    const float* __restrict__ que, unsigned short* __restrict__ Abf,
    unsigned short* __restrict__ Bbf) {
  const int AV = M_DIM * K_DIM / 4;  // 262144 float4s for A
  int i = blockIdx.x * 256 + threadIdx.x;  // grid sized exactly
  float4 x;
  unsigned short* dst;
  if (i < AV) {
    x = ((const float4*)inp)[i];
    dst = Abf + i * 4;
  } else {
    int e = (i - AV) * 4;          // element index in padded B
    int row = e >> 8;              // /256
    int col = e & 255;
    if (row < N_LUT)
      x = *(const float4*)(lut + (size_t)row * K_DIM + col);
    else if (row < N_DIM)
      x = *(const float4*)(que + (size_t)(row - N_LUT) * K_DIM + col);
    else
      x = make_float4(0.f, 0.f, 0.f, 0.f);
    dst = Bbf + e;
  }
  ushort4 o;
  o.x = f2h(x.x); o.y = f2h(x.y); o.z = f2h(x.z); o.w = f2h(x.w);
  *(ushort4*)dst = o;
}

// ---------------- GEMM: persistent-B, streaming-A ----------------
#define GLDS16(gsrc, ldst)                                                  \
  __builtin_amdgcn_global_load_lds(                                         \
      (__attribute__((address_space(1))) void*)(gsrc),                      \
      (__attribute__((address_space(3))) void*)(ldst), 16, 0, 0)

__global__ __launch_bounds__(512, 1) void gemm_kernel(
    const unsigned short* __restrict__ A, const unsigned short* __restrict__ B,
    float* __restrict__ C) {
  // B: 256 rows (C-cols) x 256 k  = 128 KiB, resident for whole block
  // A: double-buffered 32 rows x 256 k = 2 x 16 KiB
  __shared__ __align__(16) unsigned short Bs[256 * 256];
  __shared__ __align__(16) unsigned short As[2][32 * 256];

  const int t = threadIdx.x;
  const int lane = t & 63;
  const int wave = t >> 6;         // 8 waves; wave w owns C-cols w*32..+32

  const int bid = blockIdx.x;      // 252 blocks: bn fast, strip slow
  const int bn = bid % NT_N;
  const int s = bid / NT_N;        // strip 0..5
  const int bcol = bn * BN;
  // strips: subtile counts 21,21,21,21,22,22 (sum 128); starts in subtiles
  const int csub = 21 + (s >= 4 ? 1 : 0);
  const int sub0 = 21 * s + (s >= 5 ? 1 : 0);   // s=5 starts at 106
  const int row0 = sub0 * 32;

  // ---- staging geometry (rows of 256 f16 = 32 x 16B chunks) ----
  // swizzle: lds[row][c] = global[row][c ^ (row&7)]; staging thread t in
  // round r covers slot row = r*16 + (t>>5), chunk = t&31 -> fetch swizzled.
  const int srow = t >> 5;                        // 0..15 within round
  const int scs = (((t & 31) ^ (srow & 7)) * 8);  // swizzled col, elements
  const unsigned short* gbBase = B + (size_t)(bcol + srow) * K_DIM + scs;
  const unsigned short* gaBase0 = A + (size_t)(row0 + srow) * K_DIM + scs;
  const int ldsRound = wave * 2 * 256;  // wave-uniform base per round (elems)

  // A subtile: 32 rows = 2 rounds of 16
#define STAGE_A(buf, sub)                                                    \
  do {                                                                       \
    _Pragma("unroll") for (int r = 0; r < 2; ++r)                            \
      GLDS16(gaBase0 + ((size_t)(sub) * 32 + r * 16) * K_DIM,                \
             As[buf] + r * 16 * 256 + ldsRound);                             \
  } while (0)

  // ---- prologue: B once (16 rounds) + A subtile 0 ----
#pragma unroll
  for (int r = 0; r < 16; ++r)
    GLDS16(gbBase + (size_t)r * 16 * K_DIM, Bs + r * 16 * 256 + ldsRound);
  STAGE_A(0, 0);
  __syncthreads();                 // vmcnt(0) drain + barrier

  const int lr = lane & 15;
  const int rsw = lane & 7;        // = row&7 for all fragment rows
  const int cq = lane >> 4;        // 0..3
  const int cc4 = cq * 4;

  int cur = 0;
#pragma unroll 1
  for (int sub = 0; sub < csub; ++sub) {
    if (sub + 1 < csub)
      STAGE_A(cur ^ 1, sub + 1);   // prefetch next A; lands during compute

    f32x4 acc[2][2] = {};
#pragma unroll
    for (int ks = 0; ks < 8; ++ks) {           // K = 256 = 8 x 32
      const int ch = (ks * 4 + cq) ^ rsw;      // swizzled 16B chunk, 0..31
      f16x8 a[2], b[2];
#pragma unroll
      for (int i = 0; i < 2; ++i)
        a[i] = *(const f16x8*)&As[cur][(i * 16 + lr) * 256 + ch * 8];
#pragma unroll
      for (int j = 0; j < 2; ++j)
        b[j] = *(const f16x8*)&Bs[(wave * 32 + j * 16 + lr) * 256 + ch * 8];
      // swapped operands: C-row = i*16+lr, C-cols = j*16 + cc4 + reg
#pragma unroll
      for (int i = 0; i < 2; ++i)
#pragma unroll
        for (int j = 0; j < 2; ++j)
          acc[i][j] = __builtin_amdgcn_mfma_f32_16x16x32_f16(b[j], a[i],
                                                             acc[i][j], 0, 0, 0);
    }

    // store this 32x256 subtile (regs only; drains in background)
#pragma unroll
    for (int i = 0; i < 2; ++i) {
      size_t rowBase = (size_t)(row0 + sub * 32 + i * 16 + lr) * N_DIM;
#pragma unroll
      for (int j = 0; j < 2; ++j) {
        int col = bcol + wave * 32 + j * 16 + cc4;
        if (col < N_DIM)           // N_DIM%4==0: granule fully valid
          *(f32x4*)&C[rowBase + col] = acc[i][j];
      }
    }

    __syncthreads();               // next A resident; all waves done with cur
    cur ^= 1;
  }
#undef STAGE_A
}

extern "C" void kernel_launch(void* const* d_in, const int* in_sizes, int n_in,
                              void* d_out, int out_size, void* d_ws, size_t ws_size,
                              hipStream_t stream) {
  const float* inp = (const float*)d_in[0];   // inputs [4096,256]
  // d_in[1] targets, d_in[2] gt_flag: unused by the forward similarity
  const float* lut = (const float*)d_in[3];   // [5532,256]
  const float* que = (const float*)d_in[4];   // [5000,256]
  float* C = (float*)d_out;                   // [4096,10532]

  unsigned short* Abf = (unsigned short*)d_ws;
  unsigned short* Bbf = Abf + (size_t)M_DIM * K_DIM;  // ~7.7 MB of ws

  // (4096*256 + 10752*256)/4 float4s / 256 threads = 3712 blocks exact
  const int conv_blocks = (M_DIM * K_DIM / 4 + N_PAD * K_DIM / 4) / 256;
  convert_kernel<<<conv_blocks, 256, 0, stream>>>(inp, lut, que, Abf, Bbf);

  gemm_kernel<<<NSTRIP * NT_N, 512, 0, stream>>>(Abf, Bbf, C);
}

// Round 14
// 61.315 us; speedup vs baseline: 1.8765x; 1.0024x over previous
//
#include <hip/hip_runtime.h>
#include <hip/hip_bf16.h>
#include <stdint.h>

// C[4096,10532] = inputs[4096,256] @ concat(lut,queue)[10532,256]^T  (fp32 out)
// R14 = R13 (persistent-B, 252 blocks, streaming 32-row A subtiles) with the
// per-subtile __syncthreads() replaced by COUNTED vmcnt + raw s_barrier:
//   order per subtile: [2 gload_lds A(next)] sched_barrier / compute /
//   [4 C-stores] / s_waitcnt vmcnt(4) / s_barrier.
// vmcnt(4) completes the A loads (older) + previous stores while leaving the
// 4 newest C-stores in flight across the barrier -> store drain (1.23us)
// overlaps next subtile's LDS/MFMA phase (1.28us) instead of serializing.
// bn==41 blocks (branch-skipped OOB stores -> count not 4) take vmcnt(0).

#define M_DIM 4096
#define K_DIM 256
#define N_LUT 5532
#define N_Q   5000
#define N_DIM (N_LUT + N_Q)   // 10532
#define BN    256
#define NT_N  42              // ceil(10532/256)
#define N_PAD (NT_N * 256)    // 10752
#define NSTRIP 6              // m-strips; 128 subtiles of 32 rows split 21/22

typedef _Float16 f16x8 __attribute__((ext_vector_type(8)));
typedef float f32x4 __attribute__((ext_vector_type(4)));

__device__ __forceinline__ unsigned short f2h(float f) {
  union { _Float16 h; unsigned short u; } v;
  v.h = (_Float16)f;   // v_cvt_f16_f32, RNE
  return v.u;
}

// ---------------- convert fp32 -> f16 into workspace ----------------
__global__ __launch_bounds__(256) void convert_kernel(
    const float* __restrict__ inp, const float* __restrict__ lut,
    const float* __restrict__ que, unsigned short* __restrict__ Abf,
    unsigned short* __restrict__ Bbf) {
  const int AV = M_DIM * K_DIM / 4;  // 262144 float4s for A
  int i = blockIdx.x * 256 + threadIdx.x;  // grid sized exactly
  float4 x;
  unsigned short* dst;
  if (i < AV) {
    x = ((const float4*)inp)[i];
    dst = Abf + i * 4;
  } else {
    int e = (i - AV) * 4;          // element index in padded B
    int row = e >> 8;              // /256
    int col = e & 255;
    if (row < N_LUT)
      x = *(const float4*)(lut + (size_t)row * K_DIM + col);
    else if (row < N_DIM)
      x = *(const float4*)(que + (size_t)(row - N_LUT) * K_DIM + col);
    else
      x = make_float4(0.f, 0.f, 0.f, 0.f);
    dst = Bbf + e;
  }
  ushort4 o;
  o.x = f2h(x.x); o.y = f2h(x.y); o.z = f2h(x.z); o.w = f2h(x.w);
  *(ushort4*)dst = o;
}

// ---------------- GEMM: persistent-B, streaming-A ----------------
#define GLDS16(gsrc, ldst)                                                  \
  __builtin_amdgcn_global_load_lds(                                         \
      (__attribute__((address_space(1))) void*)(gsrc),                      \
      (__attribute__((address_space(3))) void*)(ldst), 16, 0, 0)

__global__ __launch_bounds__(512, 1) void gemm_kernel(
    const unsigned short* __restrict__ A, const unsigned short* __restrict__ B,
    float* __restrict__ C) {
  // B: 256 rows (C-cols) x 256 k  = 128 KiB, resident for whole block
  // A: double-buffered 32 rows x 256 k = 2 x 16 KiB
  __shared__ __align__(16) unsigned short Bs[256 * 256];
  __shared__ __align__(16) unsigned short As[2][32 * 256];

  const int t = threadIdx.x;
  const int lane = t & 63;
  const int wave = t >> 6;         // 8 waves; wave w owns C-cols w*32..+32

  const int bid = blockIdx.x;      // 252 blocks: bn fast, strip slow
  const int bn = bid % NT_N;
  const int s = bid / NT_N;        // strip 0..5
  const int bcol = bn * BN;
  const bool fullN = (bcol + BN <= N_DIM);  // false only for bn==41
  // strips: subtile counts 21,21,21,21,22,22 (sum 128)
  const int csub = 21 + (s >= 4 ? 1 : 0);
  const int sub0 = 21 * s + (s >= 5 ? 1 : 0);   // s=5 starts at 106
  const int row0 = sub0 * 32;

  // ---- staging geometry (rows of 256 f16 = 32 x 16B chunks) ----
  // swizzle: lds[row][c] = global[row][c ^ (row&7)]; staging thread t in
  // round r covers slot row = r*16 + (t>>5), chunk = t&31 -> fetch swizzled.
  const int srow = t >> 5;                        // 0..15 within round
  const int scs = (((t & 31) ^ (srow & 7)) * 8);  // swizzled col, elements
  const unsigned short* gbBase = B + (size_t)(bcol + srow) * K_DIM + scs;
  const unsigned short* gaBase0 = A + (size_t)(row0 + srow) * K_DIM + scs;
  const int ldsRound = wave * 2 * 256;  // wave-uniform base per round (elems)

  // A subtile: 32 rows = 2 rounds of 16 (2 gload_lds per thread)
#define STAGE_A(buf, sub)                                                    \
  do {                                                                       \
    _Pragma("unroll") for (int r = 0; r < 2; ++r)                            \
      GLDS16(gaBase0 + ((size_t)(sub) * 32 + r * 16) * K_DIM,                \
             As[buf] + r * 16 * 256 + ldsRound);                             \
  } while (0)

  // ---- prologue: B once (16 rounds) + A subtile 0 ----
#pragma unroll
  for (int r = 0; r < 16; ++r)
    GLDS16(gbBase + (size_t)r * 16 * K_DIM, Bs + r * 16 * 256 + ldsRound);
  STAGE_A(0, 0);
  __syncthreads();                 // full vmcnt(0) drain + barrier (once)

  const int lr = lane & 15;
  const int rsw = lane & 7;        // = row&7 for all fragment rows
  const int cq = lane >> 4;        // 0..3
  const int cc4 = cq * 4;

  int cur = 0;
#pragma unroll 1
  for (int sub = 0; sub < csub; ++sub) {
    if (sub + 1 < csub)
      STAGE_A(cur ^ 1, sub + 1);   // 2 gload_lds: oldest in vmem queue
    __builtin_amdgcn_sched_barrier(0);  // pin loads ABOVE compute+stores
                                        // (exact vmcnt counting below)

    f32x4 acc[2][2] = {};
#pragma unroll
    for (int ks = 0; ks < 8; ++ks) {           // K = 256 = 8 x 32
      const int ch = (ks * 4 + cq) ^ rsw;      // swizzled 16B chunk, 0..31
      f16x8 a[2], b[2];
#pragma unroll
      for (int i = 0; i < 2; ++i)
        a[i] = *(const f16x8*)&As[cur][(i * 16 + lr) * 256 + ch * 8];
#pragma unroll
      for (int j = 0; j < 2; ++j)
        b[j] = *(const f16x8*)&Bs[(wave * 32 + j * 16 + lr) * 256 + ch * 8];
      // swapped operands: C-row = i*16+lr, C-cols = j*16 + cc4 + reg
#pragma unroll
      for (int i = 0; i < 2; ++i)
#pragma unroll
        for (int j = 0; j < 2; ++j)
          acc[i][j] = __builtin_amdgcn_mfma_f32_16x16x32_f16(b[j], a[i],
                                                             acc[i][j], 0, 0, 0);
    }

    // 4 dwordx4 C-stores (newest in vmem queue; ride across the barrier)
#pragma unroll
    for (int i = 0; i < 2; ++i) {
      size_t rowBase = (size_t)(row0 + sub * 32 + i * 16 + lr) * N_DIM;
#pragma unroll
      for (int j = 0; j < 2; ++j) {
        int col = bcol + wave * 32 + j * 16 + cc4;
        if (col < N_DIM)           // N_DIM%4==0: granule fully valid
          *(f32x4*)&C[rowBase + col] = acc[i][j];
      }
    }

    if (sub + 1 < csub) {
      // counted wait: A(next) loads (older) + prev stores complete; THIS
      // subtile's 4 stores stay in flight and drain under next compute.
      // vmcnt BEFORE barrier: every wave's staging writes land before any
      // wave proceeds (R2 race lesson).
      if (fullN)
        asm volatile("s_waitcnt vmcnt(4)" ::: "memory");
      else
        asm volatile("s_waitcnt vmcnt(0)" ::: "memory");  // bn==41: store
                                                          // count != 4
      asm volatile("s_barrier" ::: "memory");
    }
    cur ^= 1;
  }
#undef STAGE_A
}

extern "C" void kernel_launch(void* const* d_in, const int* in_sizes, int n_in,
                              void* d_out, int out_size, void* d_ws, size_t ws_size,
                              hipStream_t stream) {
  const float* inp = (const float*)d_in[0];   // inputs [4096,256]
  // d_in[1] targets, d_in[2] gt_flag: unused by the forward similarity
  const float* lut = (const float*)d_in[3];   // [5532,256]
  const float* que = (const float*)d_in[4];   // [5000,256]
  float* C = (float*)d_out;                   // [4096,10532]

  unsigned short* Abf = (unsigned short*)d_ws;
  unsigned short* Bbf = Abf + (size_t)M_DIM * K_DIM;  // ~7.7 MB of ws

  const int conv_blocks = (M_DIM * K_DIM / 4 + N_PAD * K_DIM / 4) / 256;
  convert_kernel<<<conv_blocks, 256, 0, stream>>>(inp, lut, que, Abf, Bbf);

  gemm_kernel<<<NSTRIP * NT_N, 512, 0, stream>>>(Abf, Bbf, C);
}

// Round 15
// 48.379 us; speedup vs baseline: 2.3783x; 1.2674x over previous
//
#include <hip/hip_runtime.h>
#include <hip/hip_bf16.h>
#include <stdint.h>

// C[4096,10532] = inputs[4096,256] @ concat(lut,queue)[10532,256]^T  (fp32 out)
// R15 = R14 (persistent-B, 252 blocks, streaming 32-row A subtiles, counted
// vmcnt barrier) but with the persistent B tile held in REGISTERS instead of
// LDS: each wave's 32 C-cols x K=256 = 16 f16x8 = 64 VGPR, loaded once from
// global (Bbf padded to 10752 rows, so bn==41 loads stay in-bounds).
// Removes ALL per-subtile B ds_reads (halves LDS-port time, M1 test) and
// shrinks LDS 160->32 KB. Fabric traffic unchanged (M2 control).

#define M_DIM 4096
#define K_DIM 256
#define N_LUT 5532
#define N_Q   5000
#define N_DIM (N_LUT + N_Q)   // 10532
#define BN    256
#define NT_N  42              // ceil(10532/256)
#define N_PAD (NT_N * 256)    // 10752
#define NSTRIP 6              // m-strips; 128 subtiles of 32 rows split 21/22

typedef _Float16 f16x8 __attribute__((ext_vector_type(8)));
typedef float f32x4 __attribute__((ext_vector_type(4)));

__device__ __forceinline__ unsigned short f2h(float f) {
  union { _Float16 h; unsigned short u; } v;
  v.h = (_Float16)f;   // v_cvt_f16_f32, RNE
  return v.u;
}

// ---------------- convert fp32 -> f16 into workspace ----------------
__global__ __launch_bounds__(256) void convert_kernel(
    const float* __restrict__ inp, const float* __restrict__ lut,
    const float* __restrict__ que, unsigned short* __restrict__ Abf,
    unsigned short* __restrict__ Bbf) {
  const int AV = M_DIM * K_DIM / 4;  // 262144 float4s for A
  int i = blockIdx.x * 256 + threadIdx.x;  // grid sized exactly
  float4 x;
  unsigned short* dst;
  if (i < AV) {
    x = ((const float4*)inp)[i];
    dst = Abf + i * 4;
  } else {
    int e = (i - AV) * 4;          // element index in padded B
    int row = e >> 8;              // /256
    int col = e & 255;
    if (row < N_LUT)
      x = *(const float4*)(lut + (size_t)row * K_DIM + col);
    else if (row < N_DIM)
      x = *(const float4*)(que + (size_t)(row - N_LUT) * K_DIM + col);
    else
      x = make_float4(0.f, 0.f, 0.f, 0.f);
    dst = Bbf + e;
  }
  ushort4 o;
  o.x = f2h(x.x); o.y = f2h(x.y); o.z = f2h(x.z); o.w = f2h(x.w);
  *(ushort4*)dst = o;
}

// ---------------- GEMM: persistent-B-in-regs, streaming-A ----------------
#define GLDS16(gsrc, ldst)                                                  \
  __builtin_amdgcn_global_load_lds(                                         \
      (__attribute__((address_space(1))) void*)(gsrc),                      \
      (__attribute__((address_space(3))) void*)(ldst), 16, 0, 0)

__global__ __launch_bounds__(512, 2) void gemm_kernel(
    const unsigned short* __restrict__ A, const unsigned short* __restrict__ B,
    float* __restrict__ C) {
  // A only: double-buffered 32 rows x 256 k = 2 x 16 KiB (B lives in VGPRs)
  __shared__ __align__(16) unsigned short As[2][32 * 256];

  const int t = threadIdx.x;
  const int lane = t & 63;
  const int wave = t >> 6;         // 8 waves; wave w owns C-cols w*32..+32

  const int bid = blockIdx.x;      // 252 blocks: bn fast, strip slow
  const int bn = bid % NT_N;
  const int s = bid / NT_N;        // strip 0..5
  const int bcol = bn * BN;
  const bool fullN = (bcol + BN <= N_DIM);  // false only for bn==41
  // strips: subtile counts 21,21,21,21,22,22 (sum 128)
  const int csub = 21 + (s >= 4 ? 1 : 0);
  const int sub0 = 21 * s + (s >= 5 ? 1 : 0);   // s=5 starts at 106
  const int row0 = sub0 * 32;

  const int lr = lane & 15;
  const int rsw = lane & 7;        // = row&7 for all fragment rows
  const int cq = lane >> 4;        // 0..3
  const int cc4 = cq * 4;

  // ---- persistent B fragments -> registers (64 VGPR) ----
  // breg[j][ks]: B-row = bcol + wave*32 + j*16 + lr, k = ks*32 + cq*8.
  // Per (j,ks) instruction: 16 rows x 64 B contiguous -> 64B-sector coalesced.
  // Bbf is padded/zeroed to N_PAD rows, so bn==41 reads stay in-bounds.
  f16x8 breg[2][8];
#pragma unroll
  for (int j = 0; j < 2; ++j) {
    const unsigned short* brow =
        B + (size_t)(bcol + wave * 32 + j * 16 + lr) * K_DIM + cq * 8;
#pragma unroll
    for (int ks = 0; ks < 8; ++ks)
      breg[j][ks] = *(const f16x8*)(brow + ks * 32);
  }

  // ---- A staging geometry (rows of 256 f16 = 32 x 16B chunks) ----
  // swizzle: lds[row][c] = global[row][c ^ (row&7)]; staging thread t in
  // round r covers slot row = r*16 + (t>>5), chunk = t&31 -> fetch swizzled.
  const int srow = t >> 5;                        // 0..15 within round
  const int scs = (((t & 31) ^ (srow & 7)) * 8);  // swizzled col, elements
  const unsigned short* gaBase0 = A + (size_t)(row0 + srow) * K_DIM + scs;
  const int ldsRound = wave * 2 * 256;  // wave-uniform base per round (elems)

  // A subtile: 32 rows = 2 rounds of 16 (2 gload_lds per thread)
#define STAGE_A(buf, sub)                                                    \
  do {                                                                       \
    _Pragma("unroll") for (int r = 0; r < 2; ++r)                            \
      GLDS16(gaBase0 + ((size_t)(sub) * 32 + r * 16) * K_DIM,                \
             As[buf] + r * 16 * 256 + ldsRound);                             \
  } while (0)

  STAGE_A(0, 0);
  __syncthreads();                 // full drain + barrier (once)

  int cur = 0;
#pragma unroll 1
  for (int sub = 0; sub < csub; ++sub) {
    if (sub + 1 < csub)
      STAGE_A(cur ^ 1, sub + 1);   // 2 gload_lds: oldest in vmem queue
    __builtin_amdgcn_sched_barrier(0);  // pin loads ABOVE compute+stores

    f32x4 acc[2][2] = {};
#pragma unroll
    for (int ks = 0; ks < 8; ++ks) {           // K = 256 = 8 x 32
      const int ch = (ks * 4 + cq) ^ rsw;      // swizzled 16B chunk, 0..31
      f16x8 a[2];
#pragma unroll
      for (int i = 0; i < 2; ++i)
        a[i] = *(const f16x8*)&As[cur][(i * 16 + lr) * 256 + ch * 8];
      // swapped operands: C-row = i*16+lr, C-cols = j*16 + cc4 + reg
#pragma unroll
      for (int i = 0; i < 2; ++i)
#pragma unroll
        for (int j = 0; j < 2; ++j)
          acc[i][j] = __builtin_amdgcn_mfma_f32_16x16x32_f16(breg[j][ks], a[i],
                                                             acc[i][j], 0, 0, 0);
    }

    // 4 dwordx4 C-stores (newest in vmem queue; ride across the barrier)
#pragma unroll
    for (int i = 0; i < 2; ++i) {
      size_t rowBase = (size_t)(row0 + sub * 32 + i * 16 + lr) * N_DIM;
#pragma unroll
      for (int j = 0; j < 2; ++j) {
        int col = bcol + wave * 32 + j * 16 + cc4;
        if (col < N_DIM)           // N_DIM%4==0: granule fully valid
          *(f32x4*)&C[rowBase + col] = acc[i][j];
      }
    }

    if (sub + 1 < csub) {
      // counted wait: A(next) loads (older) complete; this subtile's 4
      // stores stay in flight and drain under next compute. vmcnt BEFORE
      // barrier (R2 race lesson). bn==41: store instr count varies -> 0.
      if (fullN)
        asm volatile("s_waitcnt vmcnt(4)" ::: "memory");
      else
        asm volatile("s_waitcnt vmcnt(0)" ::: "memory");
      asm volatile("s_barrier" ::: "memory");
    }
    cur ^= 1;
  }
#undef STAGE_A
}

extern "C" void kernel_launch(void* const* d_in, const int* in_sizes, int n_in,
                              void* d_out, int out_size, void* d_ws, size_t ws_size,
                              hipStream_t stream) {
  const float* inp = (const float*)d_in[0];   // inputs [4096,256]
  // d_in[1] targets, d_in[2] gt_flag: unused by the forward similarity
  const float* lut = (const float*)d_in[3];   // [5532,256]
  const float* que = (const float*)d_in[4];   // [5000,256]
  float* C = (float*)d_out;                   // [4096,10532]

  unsigned short* Abf = (unsigned short*)d_ws;
  unsigned short* Bbf = Abf + (size_t)M_DIM * K_DIM;  // ~7.7 MB of ws

  const int conv_blocks = (M_DIM * K_DIM / 4 + N_PAD * K_DIM / 4) / 256;
  convert_kernel<<<conv_blocks, 256, 0, stream>>>(inp, lut, que, Abf, Bbf);

  gemm_kernel<<<NSTRIP * NT_N, 512, 0, stream>>>(Abf, Bbf, C);
}